// Round 18
// baseline (59.094 us; speedup 1.0000x reference)
//
#include <hip/hip_runtime.h>
#include <math.h>

#define N_    4
#define CIN   16
#define COUT  32
#define DD    16
#define HH_   64
#define WW_   64
#define MCNT  262144.0f   // per-channel count: 4*16*64*64

typedef __attribute__((ext_vector_type(8))) short short8;
typedef __attribute__((ext_vector_type(4))) float floatx4;

__device__ __forceinline__ ushort f2bf(float f) {
    uint u = __float_as_uint(f);
    uint r = (u + 0x7fffu + ((u >> 16) & 1u)) >> 16;
    return (ushort)r;
}
__device__ __forceinline__ float bf2f(ushort v) {
    return __uint_as_float(((uint)v) << 16);
}
__device__ __forceinline__ float softplus_f(float z) {
    return fmaxf(z, 0.0f) + log1pf(expf(-fabsf(z)));
}

// ws layout (float units):
//   [0, 2162688)            xT bf16 (fp32-y fallback path only)
//   [2162688, 2169856)      wpk bf16 [14 grp][32 co][32 k]
//   [2169856, 2169920)      scs: scale[32] ++ shift[32]
//   [2169920, 2300992)      part[blk][64]
//   [2301056, 6495360)      yb bf16 [4n][32co][16d][64h][64w]
#define FAST_XT_F    0
#define FAST_WB_F    2162688
#define FAST_SC_F    2169856
#define FAST_PART_F  2169920
#define FAST_YB_F    2301056
#define FAST_BYTES_FP32Y  ((size_t)FAST_YB_F * 4)
#define FAST_BYTES_BF16Y  ((size_t)(FAST_YB_F + 4194304) * 4)
#define XROW_U16     1056   // 66 slots * 16 ci
#define XROW_CHUNKS  132    // 16B chunks per row

// ---- Kernel 0: weight prep -> global wb (1 block, 512 threads) ----
__global__ void prep_w(const float* __restrict__ weight, ushort* __restrict__ wb) {
    int t = threadIdx.x;
    int cout = t >> 4, cin = t & 15;
    const float* wp = weight + (cout * CIN + cin) * 27;
    float wv[27];
    float mx = -INFINITY;
    #pragma unroll
    for (int k = 0; k < 27; ++k) { wv[k] = wp[k]; mx = fmaxf(mx, wv[k]); }
    float cutoff = mx * 0.5f;
    const float win[3] = {0.08f, 1.0f, 0.08f};
    #pragma unroll
    for (int k = 0; k < 27; ++k) {
        float w = wv[k];
        float sg = (w > 0.0f) ? 1.0f : ((w < 0.0f) ? -1.0f : 0.0f);
        float shr = sg * fmaxf(fabsf(w) - cutoff * 0.01f, 0.0f);
        float o = (w < cutoff) ? shr : w;
        int kd = k / 9, kr = k % 9, kh = kr / 3, kw = kr % 3;
        o *= win[kd] * win[kh] * win[kw];
        int q = (kd * 3 + kh) * 3 + kw;       // 0..26
        int grp = q >> 1, half = q & 1;
        wb[(grp * COUT + cout) * 32 + half * 16 + cin] = f2bf(o);
    }
    wb[(13 * COUT + cout) * 32 + 16 + cin] = 0;
}

// ---- Kernel 1: conv, r14 geometry at 256-thread blocks (4 barrier domains/CU) ----
// Grid 1024 = n(4) x d(16) x ht(16 tiles of 4h); block 256 thr = 4 waves (wave = hq).
// Each wave serially computes cf = 0 and cf = 1 (A reloaded from L2-hot wb).
// LDS 39 KB -> 4 blocks/CU, 16 waves/CU, SINGLE dispatch round (1024 = 4*256).
__global__ __launch_bounds__(256, 4)
void conv4w(const float* __restrict__ x, const ushort* __restrict__ wb,
            const float* __restrict__ bias, ushort* __restrict__ yb,
            float* __restrict__ part) {
    __shared__ ushort xs[18 * XROW_U16];   // 38016 B [row = zdi*6+rh][66 slot][16 ci]
    __shared__ float sred[4][64];          // 1024 B

    int b = blockIdx.x;
    int n = b >> 8, d = (b >> 4) & 15, h0 = (b & 15) * 4;
    int t = threadIdx.x;
    int l = t & 63;
    int hq = t >> 6;                       // wave id = output h row
    int h = h0 + hq;
    int s = l & 15, g = l >> 4;
    int ghi = g >> 1;

    // ---- x staging with in-register transpose (identical volume to r14) ----
    if (t < 36) {       // zero halo slots 0 and 65: 18 rows x 2 cq
        int row = t >> 1, cq = t & 1;
        uint4 z = {0u, 0u, 0u, 0u};
        *(uint4*)&xs[row * XROW_U16 + 0 * 16 + cq * 8]  = z;
        *(uint4*)&xs[row * XROW_U16 + 65 * 16 + cq * 8] = z;
    }
    const int CSTRIDE = DD * HH_ * WW_;   // 65536
    for (int i = t; i < 2304; i += 256) { // 18 rows x 2 cq x 64 w
        int row = i >> 7;
        int rem = i & 127;
        int cq = rem >> 6;
        int w  = rem & 63;
        int zdi = row / 6, rh = row - zdi * 6;
        int zd = d - 1 + zdi, zh = h0 - 1 + rh;
        uint4 pk = {0u, 0u, 0u, 0u};
        if ((unsigned)zd < DD && (unsigned)zh < HH_) {
            const float* p0 = x + (((size_t)(n * CIN + cq * 8) * DD + zd) * HH_ + zh) * WW_ + w;
            float v0 = p0[0 * CSTRIDE], v1 = p0[1 * CSTRIDE];
            float v2 = p0[2 * CSTRIDE], v3 = p0[3 * CSTRIDE];
            float v4 = p0[4 * CSTRIDE], v5 = p0[5 * CSTRIDE];
            float v6 = p0[6 * CSTRIDE], v7 = p0[7 * CSTRIDE];
            pk.x = (uint)f2bf(v0) | ((uint)f2bf(v1) << 16);
            pk.y = (uint)f2bf(v2) | ((uint)f2bf(v3) << 16);
            pk.z = (uint)f2bf(v4) | ((uint)f2bf(v5) << 16);
            pk.w = (uint)f2bf(v6) | ((uint)f2bf(v7) << 16);
        }
        *(uint4*)&xs[row * XROW_U16 + (w + 1) * 16 + cq * 8] = pk;
    }
    __syncthreads();

    int hbase = hq * XROW_U16 + s * 16 + (g & 1) * 8;
    float s1[2][4], s2[2][4];
    #pragma unroll
    for (int cf = 0; cf < 2; ++cf)
        #pragma unroll
        for (int j = 0; j < 4; ++j) { s1[cf][j] = 0.f; s2[cf][j] = 0.f; }

    #pragma unroll
    for (int cf = 0; cf < 2; ++cf) {
        // A fragments for this cf half: 14 x 16B from global (L2-hot 28.7 KB)
        short8 A[14];
        #pragma unroll
        for (int grp = 0; grp < 14; ++grp)
            A[grp] = *(const short8*)&wb[(grp * COUT + cf * 16 + s) * 32 + g * 8];

        floatx4 acc[4];
        #pragma unroll
        for (int wf = 0; wf < 4; ++wf) acc[wf] = (floatx4){0.f, 0.f, 0.f, 0.f};

        #pragma unroll
        for (int grp = 0; grp < 14; ++grp) {
            const int qa = 2 * grp;
            const int qb = (grp == 13) ? 26 : 2 * grp + 1;
            const int t9a = qa / 3, t9b = qb / 3;
            const int ca = ((t9a / 3) * 6 + (t9a % 3)) * XROW_U16 + (qa % 3) * 16;
            const int cb = ((t9b / 3) * 6 + (t9b % 3)) * XROW_U16 + (qb % 3) * 16;
            int baddr = hbase + (ghi ? cb : ca);
            #pragma unroll
            for (int wf = 0; wf < 4; ++wf) {
                short8 B = *(const short8*)&xs[baddr + wf * 256];
                acc[wf] = __builtin_amdgcn_mfma_f32_16x16x32_bf16(A[grp], B, acc[wf], 0, 0, 0);
            }
        }

        // epilogue for this cf: bias + bf16 y store + stats accumulate
        #pragma unroll
        for (int j = 0; j < 4; ++j) {
            int co = cf * 16 + g * 4 + j;
            float bval = bias[co];
            size_t obase = ((size_t)(n * COUT + co) * DD + d) * (HH_ * WW_) + h * WW_ + s;
            #pragma unroll
            for (int wf = 0; wf < 4; ++wf) {
                float val = acc[wf][j] + bval;
                yb[obase + wf * 16] = f2bf(val);
                s1[cf][j] += val;
                s2[cf][j] += val * val;
            }
        }
    }

    // reduce over the 16 s-lanes sharing each co (both cf halves per wave)
    #pragma unroll
    for (int m = 1; m < 16; m <<= 1) {
        #pragma unroll
        for (int cf = 0; cf < 2; ++cf)
            #pragma unroll
            for (int j = 0; j < 4; ++j) {
                s1[cf][j] += __shfl_xor(s1[cf][j], m);
                s2[cf][j] += __shfl_xor(s2[cf][j], m);
            }
    }
    if (s == 0) {
        #pragma unroll
        for (int cf = 0; cf < 2; ++cf)
            #pragma unroll
            for (int j = 0; j < 4; ++j) {
                int co = cf * 16 + g * 4 + j;
                sred[hq][co]      = s1[cf][j];
                sred[hq][32 + co] = s2[cf][j];
            }
    }
    __syncthreads();
    if (t < 64) {
        float v = sred[0][t] + sred[1][t] + sred[2][t] + sred[3][t];
        part[(size_t)b * 64 + t] = v;
    }
}

// ---- Kernel 2: reduce part[NBLK][64] -> scale/shift ----
template <int NBLK>
__global__ __launch_bounds__(1024)
void stats_fast_t(const float* __restrict__ part, const float* __restrict__ gamma,
                  const float* __restrict__ beta, float* __restrict__ scale,
                  float* __restrict__ shift) {
    __shared__ float red[16][64];
    __shared__ float tot[64];
    const int RPG = NBLK / 16;
    int t = threadIdx.x;
    int c = t & 63, rg = t >> 6;
    const float* p = part + (size_t)rg * RPG * 64 + c;
    float s = 0.f;
    #pragma unroll 8
    for (int r = 0; r < RPG; ++r) s += p[r * 64];
    red[rg][c] = s;
    __syncthreads();
    if (t < 64) {
        float v = 0.f;
        #pragma unroll
        for (int r = 0; r < 16; ++r) v += red[r][t];
        tot[t] = v;
    }
    __syncthreads();
    if (t < 32) {
        float mean = tot[t] / MCNT;
        float var  = tot[32 + t] / MCNT - mean * mean;
        float rstd = rsqrtf(var + 1e-5f);
        float sc = gamma[t] * rstd;
        scale[t] = sc;
        shift[t] = beta[t] - mean * sc;
    }
}

// ---- Kernel 3: BN+softplus from bf16 y -> fp32 out ----
__global__ __launch_bounds__(256)
void bn_act_bf16(const ushort* __restrict__ yb, float* __restrict__ out,
                 const float* __restrict__ scale, const float* __restrict__ shift) {
    const int NV8 = (N_ * COUT * DD * HH_ * WW_) / 8;
    int stride = gridDim.x * blockDim.x;
    const short8* y8 = (const short8*)yb;
    for (int i = blockIdx.x * blockDim.x + threadIdx.x; i < NV8; i += stride) {
        int ch = (i >> 13) & 31;     // element = 8i; 65536 elems per (n,c)
        float sc = scale[ch];
        float sh = shift[ch];
        short8 yv = y8[i];
        float4 o0, o1;
        float* op0 = (float*)&o0;
        float* op1 = (float*)&o1;
        #pragma unroll
        for (int j = 0; j < 4; ++j) {
            float z = bf2f((ushort)yv[j]) * sc + sh;
            op0[j] = softplus_f(z);
        }
        #pragma unroll
        for (int j = 0; j < 4; ++j) {
            float z = bf2f((ushort)yv[4 + j]) * sc + sh;
            op1[j] = softplus_f(z);
        }
        *(float4*)&out[(size_t)i * 8]     = o0;
        *(float4*)&out[(size_t)i * 8 + 4] = o1;
    }
}

// ===================== FALLBACK PATH A (fp32 y in d_out, mid-size ws) =====================
__global__ __launch_bounds__(256, 4)
void transpose_prep(const float* __restrict__ x, const float* __restrict__ weight,
                    ushort* __restrict__ xt, ushort* __restrict__ wb) {
    __shared__ ushort lds[4 * 64 * 16];
    int b = blockIdx.x;
    int n = b >> 8, d = (b >> 4) & 15, h0 = (b & 15) * 4;
    int t = threadIdx.x;

    if (b == 0) {
        #pragma unroll
        for (int rep = 0; rep < 2; ++rep) {
            int p = t + rep * 256;
            int cout = p >> 4, cin = p & 15;
            const float* wp = weight + (cout * CIN + cin) * 27;
            float wv[27];
            float mx = -INFINITY;
            #pragma unroll
            for (int k = 0; k < 27; ++k) { wv[k] = wp[k]; mx = fmaxf(mx, wv[k]); }
            float cutoff = mx * 0.5f;
            const float win[3] = {0.08f, 1.0f, 0.08f};
            #pragma unroll
            for (int k = 0; k < 27; ++k) {
                float w = wv[k];
                float sg = (w > 0.0f) ? 1.0f : ((w < 0.0f) ? -1.0f : 0.0f);
                float shr = sg * fmaxf(fabsf(w) - cutoff * 0.01f, 0.0f);
                float o = (w < cutoff) ? shr : w;
                int kd = k / 9, kr = k % 9, kh = kr / 3, kw = kr % 3;
                o *= win[kd] * win[kh] * win[kw];
                int q = (kd * 3 + kh) * 3 + kw;
                int grp = q >> 1, half = q & 1;
                wb[(grp * COUT + cout) * 32 + half * 16 + cin] = f2bf(o);
            }
            wb[(13 * COUT + cout) * 32 + 16 + cin] = 0;
        }
    }

    int hh = t >> 6, w = t & 63;
    const float* xp = x + ((size_t)(n * CIN * DD + d) * HH_ + (h0 + hh)) * WW_ + w;
    const int CSTRIDE = DD * HH_ * WW_;
    uint rowv[8];
    #pragma unroll
    for (int cp = 0; cp < 8; ++cp) {
        float a  = xp[(2 * cp)     * CSTRIDE];
        float b2 = xp[(2 * cp + 1) * CSTRIDE];
        rowv[cp] = (uint)f2bf(a) | ((uint)f2bf(b2) << 16);
    }
    #pragma unroll
    for (int cp = 0; cp < 8; ++cp)
        *(uint*)&lds[(hh * 64 + w) * 16 + 2 * cp] = rowv[cp];
    __syncthreads();
    uint* xtg = (uint*)xt;
    for (int i = t; i < 4 * 528; i += 256) {
        int hh2 = i / 528, u = i - hh2 * 528;
        int slot = u >> 3, cp = u & 7;
        uint val = 0;
        if (slot >= 1 && slot <= 64)
            val = *(uint*)&lds[(hh2 * 64 + (slot - 1)) * 16 + 2 * cp];
        xtg[(size_t)((n * DD + d) * HH_ + (h0 + hh2)) * 528 + u] = val;
    }
}

__global__ __launch_bounds__(512, 4)
void conv_mfma_f32y(const ushort* __restrict__ xt, const ushort* __restrict__ wb,
                    const float* __restrict__ bias, float* __restrict__ outf,
                    float* __restrict__ part) {
    __shared__ ushort xs[18 * XROW_U16];
    __shared__ float sred[8][64];

    int b = blockIdx.x;
    int n = b >> 8, d = (b >> 4) & 15, h0 = (b & 15) * 4;
    int t = threadIdx.x;
    int l = t & 63;
    int wv_ = t >> 6;
    int hq = wv_ >> 1, cf = wv_ & 1;
    int h = h0 + hq;
    int s = l & 15, g = l >> 4;
    int ghi = g >> 1;

    ((float*)sred)[t] = 0.0f;

    short8 A[14];
    #pragma unroll
    for (int grp = 0; grp < 14; ++grp)
        A[grp] = *(const short8*)&wb[(grp * COUT + cf * 16 + s) * 32 + g * 8];

    const uint4* xt4 = (const uint4*)xt;
    uint4* xs4 = (uint4*)xs;
    for (int i = t; i < 18 * XROW_CHUNKS; i += 512) {
        int row = i / XROW_CHUNKS, c = i - row * XROW_CHUNKS;
        int zdi = row / 6, rh = row - zdi * 6;
        int zd = d - 1 + zdi, zh = h0 - 1 + rh;
        uint4 v = {0u, 0u, 0u, 0u};
        if ((unsigned)zd < DD && (unsigned)zh < HH_)
            v = xt4[(size_t)((n * DD + zd) * HH_ + zh) * XROW_CHUNKS + c];
        xs4[i] = v;
    }
    __syncthreads();

    floatx4 acc[4];
    #pragma unroll
    for (int wf = 0; wf < 4; ++wf) acc[wf] = (floatx4){0.f, 0.f, 0.f, 0.f};

    int hbase = hq * XROW_U16 + s * 16 + (g & 1) * 8;

    #pragma unroll
    for (int grp = 0; grp < 14; ++grp) {
        const int qa = 2 * grp;
        const int qb = (grp == 13) ? 26 : 2 * grp + 1;
        const int t9a = qa / 3, t9b = qb / 3;
        const int ca = ((t9a / 3) * 6 + (t9a % 3)) * XROW_U16 + (qa % 3) * 16;
        const int cb = ((t9b / 3) * 6 + (t9b % 3)) * XROW_U16 + (qb % 3) * 16;
        int baddr = hbase + (ghi ? cb : ca);
        #pragma unroll
        for (int wf = 0; wf < 4; ++wf) {
            short8 B = *(const short8*)&xs[baddr + wf * 256];
            acc[wf] = __builtin_amdgcn_mfma_f32_16x16x32_bf16(A[grp], B, acc[wf], 0, 0, 0);
        }
    }

    float s1[4], s2[4];
    #pragma unroll
    for (int j = 0; j < 4; ++j) { s1[j] = 0.f; s2[j] = 0.f; }
    #pragma unroll
    for (int j = 0; j < 4; ++j) {
        int co = cf * 16 + g * 4 + j;
        float bval = bias[co];
        size_t obase = ((size_t)(n * COUT + co) * DD + d) * (HH_ * WW_) + h * WW_ + s;
        #pragma unroll
        for (int wf = 0; wf < 4; ++wf) {
            float val = acc[wf][j] + bval;
            outf[obase + wf * 16] = val;
            s1[j] += val;
            s2[j] += val * val;
        }
    }
    #pragma unroll
    for (int m = 1; m < 16; m <<= 1) {
        #pragma unroll
        for (int j = 0; j < 4; ++j) {
            s1[j] += __shfl_xor(s1[j], m);
            s2[j] += __shfl_xor(s2[j], m);
        }
    }
    if (s == 0) {
        #pragma unroll
        for (int j = 0; j < 4; ++j) {
            int co = cf * 16 + g * 4 + j;
            sred[wv_][co]      = s1[j];
            sred[wv_][32 + co] = s2[j];
        }
    }
    __syncthreads();
    if (t < 64) {
        int cfh = (t >> 4) & 1;
        float v = sred[cfh][t] + sred[2 + cfh][t] + sred[4 + cfh][t] + sred[6 + cfh][t];
        part[(size_t)b * 64 + t] = v;
    }
}

__global__ void bn_act_kernel(float* __restrict__ out, const float* __restrict__ scale,
                              const float* __restrict__ shift) {
    const int NV4 = (N_ * COUT * DD * HH_ * WW_) / 4;
    int stride = gridDim.x * blockDim.x;
    float4* o4 = (float4*)out;
    for (int i = blockIdx.x * blockDim.x + threadIdx.x; i < NV4; i += stride) {
        int ch = (i >> 14) & 31;
        float sc = scale[ch];
        float sh = shift[ch];
        float4 val = o4[i];
        float* vp = (float*)&val;
        #pragma unroll
        for (int j = 0; j < 4; ++j) {
            float z = vp[j] * sc + sh;
            vp[j] = softplus_f(z);
        }
        o4[i] = val;
    }
}

// ===================== FALLBACK PATH B (fp32 VALU, small ws) =====================
#define WS_W      0
#define WS_SUM    13824
#define WS_SUMSQ  13856
#define WS_SCALE  13888
#define WS_SHIFT  13920

__global__ void prep_weights(const float* __restrict__ weight, float* __restrict__ ws) {
    int t = threadIdx.x;
    if (t < 64) ws[WS_SUM + t] = 0.0f;
    int cout = t >> 4, cin = t & 15;
    const float* wp = weight + (cout * CIN + cin) * 27;
    float wv[27];
    float mx = -INFINITY;
    #pragma unroll
    for (int k = 0; k < 27; ++k) { wv[k] = wp[k]; mx = fmaxf(mx, wv[k]); }
    float cutoff = mx * 0.5f;
    const float win[3] = {0.08f, 1.0f, 0.08f};
    #pragma unroll
    for (int k = 0; k < 27; ++k) {
        float w = wv[k];
        float s = (w > 0.0f) ? 1.0f : ((w < 0.0f) ? -1.0f : 0.0f);
        float shr = s * fmaxf(fabsf(w) - cutoff * 0.01f, 0.0f);
        float o = (w < cutoff) ? shr : w;
        int kd = k / 9, kr = k % 9, kh = kr / 3, kw = kr % 3;
        o *= win[kd] * win[kh] * win[kw];
        ws[WS_W + (cin * 27 + k) * COUT + cout] = o;
    }
}

#define RS 68
__global__ __launch_bounds__(256, 4)
void conv_kernel(const float* __restrict__ x, const float* __restrict__ bias,
                 const float* __restrict__ wsw, float* __restrict__ out,
                 float* __restrict__ sums, float* __restrict__ sumsqs) {
    __shared__ float xsf[3 * 6 * RS];
    __shared__ float sredf[16][8];
    int b = blockIdx.x;
    int n  = b >> 8;
    int d  = (b >> 4) & 15;
    int h0 = (b & 15) << 2;
    int tid = threadIdx.x;
    int wg = tid & 15;
    int cg2 = (tid >> 4) & 3;
    int v  = tid >> 6;
    int cohalf = v & 1;
    int hhalf  = v >> 1;
    int w0 = wg * 4;
    int co0 = cohalf * 16 + cg2 * 4;
    float acc[4][2][4];
    #pragma unroll
    for (int c = 0; c < 4; ++c)
        #pragma unroll
        for (int i = 0; i < 2; ++i)
            #pragma unroll
            for (int j = 0; j < 4; ++j) acc[c][i][j] = 0.0f;
    const float* xn = x + (size_t)n * CIN * DD * HH_ * WW_;
    for (int cin = 0; cin < CIN; ++cin) {
        __syncthreads();
        const float* xc = xn + cin * DD * HH_ * WW_;
        for (int idx = tid; idx < 3 * 6 * RS; idx += 256) {
            int row = idx / RS;
            int c   = idx - row * RS;
            int dd  = row / 6;
            int r   = row - dd * 6;
            int zd = d - 1 + dd;
            int zh = h0 - 1 + r;
            int w  = c - 1;
            float val = 0.0f;
            if ((unsigned)zd < DD && (unsigned)zh < HH_ && (unsigned)w < WW_)
                val = xc[(zd * HH_ + zh) * WW_ + w];
            xsf[idx] = val;
        }
        __syncthreads();
        const float* wc = wsw + cin * 27 * COUT + co0;
        #pragma unroll 1
        for (int kd = 0; kd < 3; ++kd) {
            float4 wvv[9];
            #pragma unroll
            for (int j = 0; j < 9; ++j)
                wvv[j] = *(const float4*)&wc[(kd * 9 + j) * COUT];
            const float* xp = &xsf[(kd * 6 + hhalf * 2) * RS];
            #pragma unroll
            for (int rr = 0; rr < 4; ++rr) {
                const float* xr_ = &xp[rr * RS + w0];
                float4 xm = *(const float4*)xr_;
                float x4 = xr_[4];
                float x5 = xr_[5];
                float xv[6] = {xm.x, xm.y, xm.z, xm.w, x4, x5};
                #pragma unroll
                for (int kh = 0; kh < 3; ++kh) {
                    int i = rr - kh;
                    if (i < 0 || i > 1) continue;
                    #pragma unroll
                    for (int kw = 0; kw < 3; ++kw) {
                        float4 w4 = wvv[kh * 3 + kw];
                        #pragma unroll
                        for (int j = 0; j < 4; ++j) {
                            float xx = xv[j + kw];
                            acc[0][i][j] = fmaf(w4.x, xx, acc[0][i][j]);
                            acc[1][i][j] = fmaf(w4.y, xx, acc[1][i][j]);
                            acc[2][i][j] = fmaf(w4.z, xx, acc[2][i][j]);
                            acc[3][i][j] = fmaf(w4.w, xx, acc[3][i][j]);
                        }
                    }
                }
            }
        }
    }
    float s1[4], s2[4];
    #pragma unroll
    for (int c = 0; c < 4; ++c) {
        float bval = bias[co0 + c];
        s1[c] = 0.0f; s2[c] = 0.0f;
        #pragma unroll
        for (int i = 0; i < 2; ++i) {
            float4 o;
            float* op = (float*)&o;
            #pragma unroll
            for (int j = 0; j < 4; ++j) {
                float val = acc[c][i][j] + bval;
                op[j] = val;
                s1[c] += val;
                s2[c] += val * val;
            }
            int hh = h0 + hhalf * 2 + i;
            *(float4*)&out[((((size_t)n * COUT + co0 + c) * DD + d) * HH_ + hh) * WW_ + w0] = o;
        }
    }
    #pragma unroll
    for (int m = 1; m < 16; m <<= 1) {
        #pragma unroll
        for (int c = 0; c < 4; ++c) {
            s1[c] += __shfl_xor(s1[c], m);
            s2[c] += __shfl_xor(s2[c], m);
        }
    }
    if ((tid & 15) == 0) {
        int gg = tid >> 4;
        #pragma unroll
        for (int c = 0; c < 4; ++c) { sredf[gg][c] = s1[c]; sredf[gg][4 + c] = s2[c]; }
    }
    __syncthreads();
    if (tid < 64) {
        int co   = tid & 31;
        int kind = tid >> 5;
        int ch   = (co >> 4) & 1;
        int cgg  = (co >> 2) & 3;
        int c    = co & 3;
        float val = sredf[ch * 4 + cgg][kind * 4 + c] + sredf[(ch + 2) * 4 + cgg][kind * 4 + c];
        atomicAdd(kind ? &sumsqs[co] : &sums[co], val);
    }
}

__global__ void stats_kernel(const float* __restrict__ gamma, const float* __restrict__ beta,
                             const float* __restrict__ sums, const float* __restrict__ sumsqs,
                             float* __restrict__ scale, float* __restrict__ shift) {
    int c = threadIdx.x;
    if (c >= 32) return;
    float mean = sums[c] / MCNT;
    float var  = sumsqs[c] / MCNT - mean * mean;
    float rstd = rsqrtf(var + 1e-5f);
    float sc = gamma[c] * rstd;
    scale[c] = sc;
    shift[c] = beta[c] - mean * sc;
}

extern "C" void kernel_launch(void* const* d_in, const int* in_sizes, int n_in,
                              void* d_out, int out_size, void* d_ws, size_t ws_size,
                              hipStream_t stream) {
    const float* x      = (const float*)d_in[0];
    const float* weight = (const float*)d_in[1];
    const float* bias   = (const float*)d_in[2];
    const float* gamma  = (const float*)d_in[3];
    const float* beta   = (const float*)d_in[4];
    float* out = (float*)d_out;
    float* wsf = (float*)d_ws;

    float* scale = wsf + FAST_SC_F;
    float* shift = wsf + FAST_SC_F + 32;
    float* part  = wsf + FAST_PART_F;
    ushort* wb   = (ushort*)(wsf + FAST_WB_F);

    if (ws_size >= FAST_BYTES_BF16Y) {
        ushort* yb = (ushort*)(wsf + FAST_YB_F);
        hipLaunchKernelGGL(prep_w, dim3(1), dim3(512), 0, stream, weight, wb);
        hipLaunchKernelGGL(conv4w, dim3(1024), dim3(256), 0, stream,
                           x, wb, bias, yb, part);
        hipLaunchKernelGGL((stats_fast_t<1024>), dim3(1), dim3(1024), 0, stream,
                           part, gamma, beta, scale, shift);
        hipLaunchKernelGGL(bn_act_bf16, dim3(2048), dim3(256), 0, stream,
                           yb, out, scale, shift);
    } else if (ws_size >= FAST_BYTES_FP32Y) {
        ushort* xt = (ushort*)(wsf + FAST_XT_F);
        hipLaunchKernelGGL(transpose_prep, dim3(1024), dim3(256), 0, stream,
                           x, weight, xt, wb);
        hipLaunchKernelGGL(conv_mfma_f32y, dim3(1024), dim3(512), 0, stream,
                           xt, wb, bias, out, part);
        hipLaunchKernelGGL((stats_fast_t<1024>), dim3(1), dim3(1024), 0, stream,
                           part, gamma, beta, scale, shift);
        hipLaunchKernelGGL(bn_act_kernel, dim3(2048), dim3(256), 0, stream,
                           out, scale, shift);
    } else {
        hipLaunchKernelGGL(prep_weights, dim3(1), dim3(512), 0, stream, weight, wsf);
        hipLaunchKernelGGL(conv_kernel, dim3(1024), dim3(256), 0, stream,
                           x, bias, wsf + WS_W, out, wsf + WS_SUM, wsf + WS_SUMSQ);
        hipLaunchKernelGGL(stats_kernel, dim3(1), dim3(64), 0, stream,
                           gamma, beta, wsf + WS_SUM, wsf + WS_SUMSQ, wsf + WS_SCALE, wsf + WS_SHIFT);
        hipLaunchKernelGGL(bn_act_kernel, dim3(2048), dim3(256), 0, stream,
                           out, wsf + WS_SCALE, wsf + WS_SHIFT);
    }
}

// Round 20
// 53.944 us; speedup vs baseline: 1.0955x; 1.0955x over previous
//
#include <hip/hip_runtime.h>
#include <math.h>

#define N_    4
#define CIN   16
#define COUT  32
#define DD    16
#define HH_   64
#define WW_   64
#define MCNT  262144.0f   // per-channel count: 4*16*64*64

typedef __attribute__((ext_vector_type(8))) short short8;
typedef __attribute__((ext_vector_type(4))) float floatx4;

__device__ __forceinline__ ushort f2bf(float f) {
    uint u = __float_as_uint(f);
    uint r = (u + 0x7fffu + ((u >> 16) & 1u)) >> 16;
    return (ushort)r;
}
__device__ __forceinline__ float bf2f(ushort v) {
    return __uint_as_float(((uint)v) << 16);
}
__device__ __forceinline__ float softplus_f(float z) {
    return fmaxf(z, 0.0f) + log1pf(expf(-fabsf(z)));
}

// ws layout (float units):
//   [0, 2162688)            xT bf16 (fp32-y fallback path only)
//   [2162688, 2169856)      wpk bf16 [14 grp][32 co][32 k]   (fallback A)
//   [2169856, 2169920)      scs: scale[32] ++ shift[32]
//   [2169920, 2235456)      part[1024 blk][64]
//   [2301056, 6495360)      yb bf16 [4n][32co][16d][64h][64w]
#define FAST_XT_F    0
#define FAST_WB_F    2162688
#define FAST_SC_F    2169856
#define FAST_PART_F  2169920
#define FAST_YB_F    2301056
#define FAST_BYTES_FP32Y  ((size_t)FAST_YB_F * 4)
#define FAST_BYTES_BF16Y  ((size_t)(FAST_YB_F + 4194304) * 4)
#define XROW_U16     1056   // 66 slots * 16 ci
#define XROW_CHUNKS  132    // 16B chunks per row
#define WROW_U16     40     // padded wlds row stride (80 B)

// ===================== Kernel 1: fused conv (round-14 proven) =====================
// Per block: in-LDS weight prep + in-LDS x transpose of the 18-row halo, then the
// MFMA loop; y -> bf16 buffer, stats -> private part row (no atomics).
__global__ __launch_bounds__(512, 4)
void conv_direct(const float* __restrict__ x, const float* __restrict__ weight,
                 const float* __restrict__ bias, ushort* __restrict__ yb,
                 float* __restrict__ part) {
    __shared__ ushort xs[18 * XROW_U16];          // 38016 B
    __shared__ ushort wlds[14 * COUT * WROW_U16]; // 35840 B
    __shared__ float sred[8][64];                 // 2048 B

    int b = blockIdx.x;                 // 1024 = n(4) x d(16) x ht(16)
    int n = b >> 8, d = (b >> 4) & 15, h0 = (b & 15) * 4;
    int t = threadIdx.x;
    int l = t & 63;
    int wv_ = t >> 6;
    int hq = wv_ >> 1, cf = wv_ & 1;
    int h = h0 + hq;
    int s = l & 15, g = l >> 4;
    int ghi = g >> 1;

    ((float*)sred)[t] = 0.0f;

    // ---- weight prep into wlds: thread owns one (cout,cin) pair ----
    {
        int cout = t >> 4, cin = t & 15;
        const float* wp = weight + (cout * CIN + cin) * 27;
        float wv[27];
        float mx = -INFINITY;
        #pragma unroll
        for (int k = 0; k < 27; ++k) { wv[k] = wp[k]; mx = fmaxf(mx, wv[k]); }
        float cutoff = mx * 0.5f;
        const float win[3] = {0.08f, 1.0f, 0.08f};
        #pragma unroll
        for (int k = 0; k < 27; ++k) {
            float w = wv[k];
            float sg = (w > 0.0f) ? 1.0f : ((w < 0.0f) ? -1.0f : 0.0f);
            float shr = sg * fmaxf(fabsf(w) - cutoff * 0.01f, 0.0f);
            float o = (w < cutoff) ? shr : w;
            int kd = k / 9, kr = k % 9, kh = kr / 3, kw = kr % 3;
            o *= win[kd] * win[kh] * win[kw];
            int q = (kd * 3 + kh) * 3 + kw;         // 0..26
            int grp = q >> 1, half = q & 1;
            wlds[(grp * COUT + cout) * WROW_U16 + half * 16 + cin] = f2bf(o);
        }
        wlds[(13 * COUT + cout) * WROW_U16 + 16 + cin] = 0;  // grp13 upper half
    }

    // ---- x staging with in-register transpose ----
    for (int i = t; i < 18 * 2; i += 512) {
        int row = i >> 1, cq = i & 1;
        uint4 z = {0u, 0u, 0u, 0u};
        *(uint4*)&xs[row * XROW_U16 + 0 * 16 + cq * 8]  = z;
        *(uint4*)&xs[row * XROW_U16 + 65 * 16 + cq * 8] = z;
    }
    const int CSTRIDE = DD * HH_ * WW_;   // 65536
    for (int i = t; i < 2304; i += 512) { // 18 rows x 2 cq x 64 w
        int row = i >> 7;
        int rem = i & 127;
        int cq = rem >> 6;               // ci half: ci = cq*8 .. +7
        int w  = rem & 63;
        int zdi = row / 6, rh = row - zdi * 6;
        int zd = d - 1 + zdi, zh = h0 - 1 + rh;
        uint4 pk = {0u, 0u, 0u, 0u};
        if ((unsigned)zd < DD && (unsigned)zh < HH_) {
            const float* p0 = x + (((size_t)(n * CIN + cq * 8) * DD + zd) * HH_ + zh) * WW_ + w;
            float v0 = p0[0 * CSTRIDE], v1 = p0[1 * CSTRIDE];
            float v2 = p0[2 * CSTRIDE], v3 = p0[3 * CSTRIDE];
            float v4 = p0[4 * CSTRIDE], v5 = p0[5 * CSTRIDE];
            float v6 = p0[6 * CSTRIDE], v7 = p0[7 * CSTRIDE];
            pk.x = (uint)f2bf(v0) | ((uint)f2bf(v1) << 16);
            pk.y = (uint)f2bf(v2) | ((uint)f2bf(v3) << 16);
            pk.z = (uint)f2bf(v4) | ((uint)f2bf(v5) << 16);
            pk.w = (uint)f2bf(v6) | ((uint)f2bf(v7) << 16);
        }
        *(uint4*)&xs[row * XROW_U16 + (w + 1) * 16 + cq * 8] = pk;
    }
    __syncthreads();

    // ---- A fragments from wlds ----
    short8 A[14];
    #pragma unroll
    for (int grp = 0; grp < 14; ++grp)
        A[grp] = *(const short8*)&wlds[(grp * COUT + cf * 16 + s) * WROW_U16 + g * 8];

    floatx4 acc[4];
    #pragma unroll
    for (int wf = 0; wf < 4; ++wf) acc[wf] = (floatx4){0.f, 0.f, 0.f, 0.f};

    int hbase = hq * XROW_U16 + s * 16 + (g & 1) * 8;

    #pragma unroll
    for (int grp = 0; grp < 14; ++grp) {
        const int qa = 2 * grp;
        const int qb = (grp == 13) ? 26 : 2 * grp + 1;
        const int t9a = qa / 3, t9b = qb / 3;
        const int ca = ((t9a / 3) * 6 + (t9a % 3)) * XROW_U16 + (qa % 3) * 16;
        const int cb = ((t9b / 3) * 6 + (t9b % 3)) * XROW_U16 + (qb % 3) * 16;
        int baddr = hbase + (ghi ? cb : ca);
        #pragma unroll
        for (int wf = 0; wf < 4; ++wf) {
            short8 B = *(const short8*)&xs[baddr + wf * 256];
            acc[wf] = __builtin_amdgcn_mfma_f32_16x16x32_bf16(A[grp], B, acc[wf], 0, 0, 0);
        }
    }

    float s1[4], s2[4];
    #pragma unroll
    for (int j = 0; j < 4; ++j) { s1[j] = 0.f; s2[j] = 0.f; }
    #pragma unroll
    for (int j = 0; j < 4; ++j) {
        int co = cf * 16 + g * 4 + j;
        float bval = bias[co];
        size_t obase = ((size_t)(n * COUT + co) * DD + d) * (HH_ * WW_) + h * WW_ + s;
        #pragma unroll
        for (int wf = 0; wf < 4; ++wf) {
            float val = acc[wf][j] + bval;
            yb[obase + wf * 16] = f2bf(val);
            s1[j] += val;
            s2[j] += val * val;
        }
    }
    #pragma unroll
    for (int m = 1; m < 16; m <<= 1) {
        #pragma unroll
        for (int j = 0; j < 4; ++j) {
            s1[j] += __shfl_xor(s1[j], m);
            s2[j] += __shfl_xor(s2[j], m);
        }
    }
    if (s == 0) {
        #pragma unroll
        for (int j = 0; j < 4; ++j) {
            int co = cf * 16 + g * 4 + j;
            sred[wv_][co]      = s1[j];
            sred[wv_][32 + co] = s2[j];
        }
    }
    __syncthreads();
    if (t < 64) {
        int cfh = (t >> 4) & 1;
        float v = sred[cfh][t] + sred[2 + cfh][t] + sred[4 + cfh][t] + sred[6 + cfh][t];
        part[(size_t)b * 64 + t] = v;
    }
}

// ---- Kernel 2: reduce part[NBLK][64] -> scale/shift ----
template <int NBLK>
__global__ __launch_bounds__(1024)
void stats_fast_t(const float* __restrict__ part, const float* __restrict__ gamma,
                  const float* __restrict__ beta, float* __restrict__ scale,
                  float* __restrict__ shift) {
    __shared__ float red[16][64];
    __shared__ float tot[64];
    const int RPG = NBLK / 16;
    int t = threadIdx.x;
    int c = t & 63, rg = t >> 6;
    const float* p = part + (size_t)rg * RPG * 64 + c;
    float s = 0.f;
    #pragma unroll 8
    for (int r = 0; r < RPG; ++r) s += p[r * 64];
    red[rg][c] = s;
    __syncthreads();
    if (t < 64) {
        float v = 0.f;
        #pragma unroll
        for (int r = 0; r < 16; ++r) v += red[r][t];
        tot[t] = v;
    }
    __syncthreads();
    if (t < 32) {
        float mean = tot[t] / MCNT;
        float var  = tot[32 + t] / MCNT - mean * mean;
        float rstd = rsqrtf(var + 1e-5f);
        float sc = gamma[t] * rstd;
        scale[t] = sc;
        shift[t] = beta[t] - mean * sc;
    }
}

// ---- Kernel 3: BN+softplus from bf16 y -> fp32 out ----
__global__ __launch_bounds__(256)
void bn_act_bf16(const ushort* __restrict__ yb, float* __restrict__ out,
                 const float* __restrict__ scale, const float* __restrict__ shift) {
    const int NV8 = (N_ * COUT * DD * HH_ * WW_) / 8;
    int stride = gridDim.x * blockDim.x;
    const short8* y8 = (const short8*)yb;
    for (int i = blockIdx.x * blockDim.x + threadIdx.x; i < NV8; i += stride) {
        int ch = (i >> 13) & 31;     // element = 8i; 65536 elems per (n,c)
        float sc = scale[ch];
        float sh = shift[ch];
        short8 yv = y8[i];
        float4 o0, o1;
        float* op0 = (float*)&o0;
        float* op1 = (float*)&o1;
        #pragma unroll
        for (int j = 0; j < 4; ++j) {
            float z = bf2f((ushort)yv[j]) * sc + sh;
            op0[j] = softplus_f(z);
        }
        #pragma unroll
        for (int j = 0; j < 4; ++j) {
            float z = bf2f((ushort)yv[4 + j]) * sc + sh;
            op1[j] = softplus_f(z);
        }
        *(float4*)&out[(size_t)i * 8]     = o0;
        *(float4*)&out[(size_t)i * 8 + 4] = o1;
    }
}

// ===================== FALLBACK PATH A (fp32 y in d_out, mid-size ws) =====================
__global__ __launch_bounds__(256, 4)
void transpose_prep(const float* __restrict__ x, const float* __restrict__ weight,
                    ushort* __restrict__ xt, ushort* __restrict__ wb) {
    __shared__ ushort lds[4 * 64 * 16];
    int b = blockIdx.x;
    int n = b >> 8, d = (b >> 4) & 15, h0 = (b & 15) * 4;
    int t = threadIdx.x;

    if (b == 0) {
        #pragma unroll
        for (int rep = 0; rep < 2; ++rep) {
            int p = t + rep * 256;
            int cout = p >> 4, cin = p & 15;
            const float* wp = weight + (cout * CIN + cin) * 27;
            float wv[27];
            float mx = -INFINITY;
            #pragma unroll
            for (int k = 0; k < 27; ++k) { wv[k] = wp[k]; mx = fmaxf(mx, wv[k]); }
            float cutoff = mx * 0.5f;
            const float win[3] = {0.08f, 1.0f, 0.08f};
            #pragma unroll
            for (int k = 0; k < 27; ++k) {
                float w = wv[k];
                float sg = (w > 0.0f) ? 1.0f : ((w < 0.0f) ? -1.0f : 0.0f);
                float shr = sg * fmaxf(fabsf(w) - cutoff * 0.01f, 0.0f);
                float o = (w < cutoff) ? shr : w;
                int kd = k / 9, kr = k % 9, kh = kr / 3, kw = kr % 3;
                o *= win[kd] * win[kh] * win[kw];
                int q = (kd * 3 + kh) * 3 + kw;
                int grp = q >> 1, half = q & 1;
                wb[(grp * COUT + cout) * 32 + half * 16 + cin] = f2bf(o);
            }
            wb[(13 * COUT + cout) * 32 + 16 + cin] = 0;
        }
    }

    int hh = t >> 6, w = t & 63;
    const float* xp = x + ((size_t)(n * CIN * DD + d) * HH_ + (h0 + hh)) * WW_ + w;
    const int CSTRIDE = DD * HH_ * WW_;
    uint rowv[8];
    #pragma unroll
    for (int cp = 0; cp < 8; ++cp) {
        float a  = xp[(2 * cp)     * CSTRIDE];
        float b2 = xp[(2 * cp + 1) * CSTRIDE];
        rowv[cp] = (uint)f2bf(a) | ((uint)f2bf(b2) << 16);
    }
    #pragma unroll
    for (int cp = 0; cp < 8; ++cp)
        *(uint*)&lds[(hh * 64 + w) * 16 + 2 * cp] = rowv[cp];
    __syncthreads();
    uint* xtg = (uint*)xt;
    for (int i = t; i < 4 * 528; i += 256) {
        int hh2 = i / 528, u = i - hh2 * 528;
        int slot = u >> 3, cp = u & 7;
        uint val = 0;
        if (slot >= 1 && slot <= 64)
            val = *(uint*)&lds[(hh2 * 64 + (slot - 1)) * 16 + 2 * cp];
        xtg[(size_t)((n * DD + d) * HH_ + (h0 + hh2)) * 528 + u] = val;
    }
}

__global__ __launch_bounds__(512, 4)
void conv_mfma_f32y(const ushort* __restrict__ xt, const ushort* __restrict__ wb,
                    const float* __restrict__ bias, float* __restrict__ outf,
                    float* __restrict__ part) {
    __shared__ ushort xs[18 * XROW_U16];
    __shared__ float sred[8][64];

    int b = blockIdx.x;
    int n = b >> 8, d = (b >> 4) & 15, h0 = (b & 15) * 4;
    int t = threadIdx.x;
    int l = t & 63;
    int wv_ = t >> 6;
    int hq = wv_ >> 1, cf = wv_ & 1;
    int h = h0 + hq;
    int s = l & 15, g = l >> 4;
    int ghi = g >> 1;

    ((float*)sred)[t] = 0.0f;

    short8 A[14];
    #pragma unroll
    for (int grp = 0; grp < 14; ++grp)
        A[grp] = *(const short8*)&wb[(grp * COUT + cf * 16 + s) * 32 + g * 8];

    const uint4* xt4 = (const uint4*)xt;
    uint4* xs4 = (uint4*)xs;
    for (int i = t; i < 18 * XROW_CHUNKS; i += 512) {
        int row = i / XROW_CHUNKS, c = i - row * XROW_CHUNKS;
        int zdi = row / 6, rh = row - zdi * 6;
        int zd = d - 1 + zdi, zh = h0 - 1 + rh;
        uint4 v = {0u, 0u, 0u, 0u};
        if ((unsigned)zd < DD && (unsigned)zh < HH_)
            v = xt4[(size_t)((n * DD + zd) * HH_ + zh) * XROW_CHUNKS + c];
        xs4[i] = v;
    }
    __syncthreads();

    floatx4 acc[4];
    #pragma unroll
    for (int wf = 0; wf < 4; ++wf) acc[wf] = (floatx4){0.f, 0.f, 0.f, 0.f};

    int hbase = hq * XROW_U16 + s * 16 + (g & 1) * 8;

    #pragma unroll
    for (int grp = 0; grp < 14; ++grp) {
        const int qa = 2 * grp;
        const int qb = (grp == 13) ? 26 : 2 * grp + 1;
        const int t9a = qa / 3, t9b = qb / 3;
        const int ca = ((t9a / 3) * 6 + (t9a % 3)) * XROW_U16 + (qa % 3) * 16;
        const int cb = ((t9b / 3) * 6 + (t9b % 3)) * XROW_U16 + (qb % 3) * 16;
        int baddr = hbase + (ghi ? cb : ca);
        #pragma unroll
        for (int wf = 0; wf < 4; ++wf) {
            short8 B = *(const short8*)&xs[baddr + wf * 256];
            acc[wf] = __builtin_amdgcn_mfma_f32_16x16x32_bf16(A[grp], B, acc[wf], 0, 0, 0);
        }
    }

    float s1[4], s2[4];
    #pragma unroll
    for (int j = 0; j < 4; ++j) { s1[j] = 0.f; s2[j] = 0.f; }
    #pragma unroll
    for (int j = 0; j < 4; ++j) {
        int co = cf * 16 + g * 4 + j;
        float bval = bias[co];
        size_t obase = ((size_t)(n * COUT + co) * DD + d) * (HH_ * WW_) + h * WW_ + s;
        #pragma unroll
        for (int wf = 0; wf < 4; ++wf) {
            float val = acc[wf][j] + bval;
            outf[obase + wf * 16] = val;
            s1[j] += val;
            s2[j] += val * val;
        }
    }
    #pragma unroll
    for (int m = 1; m < 16; m <<= 1) {
        #pragma unroll
        for (int j = 0; j < 4; ++j) {
            s1[j] += __shfl_xor(s1[j], m);
            s2[j] += __shfl_xor(s2[j], m);
        }
    }
    if (s == 0) {
        #pragma unroll
        for (int j = 0; j < 4; ++j) {
            int co = cf * 16 + g * 4 + j;
            sred[wv_][co]      = s1[j];
            sred[wv_][32 + co] = s2[j];
        }
    }
    __syncthreads();
    if (t < 64) {
        int cfh = (t >> 4) & 1;
        float v = sred[cfh][t] + sred[2 + cfh][t] + sred[4 + cfh][t] + sred[6 + cfh][t];
        part[(size_t)b * 64 + t] = v;
    }
}

__global__ void bn_act_kernel(float* __restrict__ out, const float* __restrict__ scale,
                              const float* __restrict__ shift) {
    const int NV4 = (N_ * COUT * DD * HH_ * WW_) / 4;
    int stride = gridDim.x * blockDim.x;
    float4* o4 = (float4*)out;
    for (int i = blockIdx.x * blockDim.x + threadIdx.x; i < NV4; i += stride) {
        int ch = (i >> 14) & 31;
        float sc = scale[ch];
        float sh = shift[ch];
        float4 val = o4[i];
        float* vp = (float*)&val;
        #pragma unroll
        for (int j = 0; j < 4; ++j) {
            float z = vp[j] * sc + sh;
            vp[j] = softplus_f(z);
        }
        o4[i] = val;
    }
}

// ===================== FALLBACK PATH B (fp32 VALU, small ws) =====================
#define WS_W      0
#define WS_SUM    13824
#define WS_SUMSQ  13856
#define WS_SCALE  13888
#define WS_SHIFT  13920

__global__ void prep_weights(const float* __restrict__ weight, float* __restrict__ ws) {
    int t = threadIdx.x;
    if (t < 64) ws[WS_SUM + t] = 0.0f;
    int cout = t >> 4, cin = t & 15;
    const float* wp = weight + (cout * CIN + cin) * 27;
    float wv[27];
    float mx = -INFINITY;
    #pragma unroll
    for (int k = 0; k < 27; ++k) { wv[k] = wp[k]; mx = fmaxf(mx, wv[k]); }
    float cutoff = mx * 0.5f;
    const float win[3] = {0.08f, 1.0f, 0.08f};
    #pragma unroll
    for (int k = 0; k < 27; ++k) {
        float w = wv[k];
        float s = (w > 0.0f) ? 1.0f : ((w < 0.0f) ? -1.0f : 0.0f);
        float shr = s * fmaxf(fabsf(w) - cutoff * 0.01f, 0.0f);
        float o = (w < cutoff) ? shr : w;
        int kd = k / 9, kr = k % 9, kh = kr / 3, kw = kr % 3;
        o *= win[kd] * win[kh] * win[kw];
        ws[WS_W + (cin * 27 + k) * COUT + cout] = o;
    }
}

#define RS 68
__global__ __launch_bounds__(256, 4)
void conv_kernel(const float* __restrict__ x, const float* __restrict__ bias,
                 const float* __restrict__ wsw, float* __restrict__ out,
                 float* __restrict__ sums, float* __restrict__ sumsqs) {
    __shared__ float xsf[3 * 6 * RS];
    __shared__ float sredf[16][8];
    int b = blockIdx.x;
    int n  = b >> 8;
    int d  = (b >> 4) & 15;
    int h0 = (b & 15) << 2;
    int tid = threadIdx.x;
    int wg = tid & 15;
    int cg2 = (tid >> 4) & 3;
    int v  = tid >> 6;
    int cohalf = v & 1;
    int hhalf  = v >> 1;
    int w0 = wg * 4;
    int co0 = cohalf * 16 + cg2 * 4;
    float acc[4][2][4];
    #pragma unroll
    for (int c = 0; c < 4; ++c)
        #pragma unroll
        for (int i = 0; i < 2; ++i)
            #pragma unroll
            for (int j = 0; j < 4; ++j) acc[c][i][j] = 0.0f;
    const float* xn = x + (size_t)n * CIN * DD * HH_ * WW_;
    for (int cin = 0; cin < CIN; ++cin) {
        __syncthreads();
        const float* xc = xn + cin * DD * HH_ * WW_;
        for (int idx = tid; idx < 3 * 6 * RS; idx += 256) {
            int row = idx / RS;
            int c   = idx - row * RS;
            int dd  = row / 6;
            int r   = row - dd * 6;
            int zd = d - 1 + dd;
            int zh = h0 - 1 + r;
            int w  = c - 1;
            float val = 0.0f;
            if ((unsigned)zd < DD && (unsigned)zh < HH_ && (unsigned)w < WW_)
                val = xc[(zd * HH_ + zh) * WW_ + w];
            xsf[idx] = val;
        }
        __syncthreads();
        const float* wc = wsw + cin * 27 * COUT + co0;
        #pragma unroll 1
        for (int kd = 0; kd < 3; ++kd) {
            float4 wvv[9];
            #pragma unroll
            for (int j = 0; j < 9; ++j)
                wvv[j] = *(const float4*)&wc[(kd * 9 + j) * COUT];
            const float* xp = &xsf[(kd * 6 + hhalf * 2) * RS];
            #pragma unroll
            for (int rr = 0; rr < 4; ++rr) {
                const float* xr_ = &xp[rr * RS + w0];
                float4 xm = *(const float4*)xr_;
                float x4 = xr_[4];
                float x5 = xr_[5];
                float xv[6] = {xm.x, xm.y, xm.z, xm.w, x4, x5};
                #pragma unroll
                for (int kh = 0; kh < 3; ++kh) {
                    int i = rr - kh;
                    if (i < 0 || i > 1) continue;
                    #pragma unroll
                    for (int kw = 0; kw < 3; ++kw) {
                        float4 w4 = wvv[kh * 3 + kw];
                        #pragma unroll
                        for (int j = 0; j < 4; ++j) {
                            float xx = xv[j + kw];
                            acc[0][i][j] = fmaf(w4.x, xx, acc[0][i][j]);
                            acc[1][i][j] = fmaf(w4.y, xx, acc[1][i][j]);
                            acc[2][i][j] = fmaf(w4.z, xx, acc[2][i][j]);
                            acc[3][i][j] = fmaf(w4.w, xx, acc[3][i][j]);
                        }
                    }
                }
            }
        }
    }
    float s1[4], s2[4];
    #pragma unroll
    for (int c = 0; c < 4; ++c) {
        float bval = bias[co0 + c];
        s1[c] = 0.0f; s2[c] = 0.0f;
        #pragma unroll
        for (int i = 0; i < 2; ++i) {
            float4 o;
            float* op = (float*)&o;
            #pragma unroll
            for (int j = 0; j < 4; ++j) {
                float val = acc[c][i][j] + bval;
                op[j] = val;
                s1[c] += val;
                s2[c] += val * val;
            }
            int hh = h0 + hhalf * 2 + i;
            *(float4*)&out[((((size_t)n * COUT + co0 + c) * DD + d) * HH_ + hh) * WW_ + w0] = o;
        }
    }
    #pragma unroll
    for (int m = 1; m < 16; m <<= 1) {
        #pragma unroll
        for (int c = 0; c < 4; ++c) {
            s1[c] += __shfl_xor(s1[c], m);
            s2[c] += __shfl_xor(s2[c], m);
        }
    }
    if ((tid & 15) == 0) {
        int gg = tid >> 4;
        #pragma unroll
        for (int c = 0; c < 4; ++c) { sredf[gg][c] = s1[c]; sredf[gg][4 + c] = s2[c]; }
    }
    __syncthreads();
    if (tid < 64) {
        int co   = tid & 31;
        int kind = tid >> 5;
        int ch   = (co >> 4) & 1;
        int cgg  = (co >> 2) & 3;
        int c    = co & 3;
        float val = sredf[ch * 4 + cgg][kind * 4 + c] + sredf[(ch + 2) * 4 + cgg][kind * 4 + c];
        atomicAdd(kind ? &sumsqs[co] : &sums[co], val);
    }
}

__global__ void stats_kernel(const float* __restrict__ gamma, const float* __restrict__ beta,
                             const float* __restrict__ sums, const float* __restrict__ sumsqs,
                             float* __restrict__ scale, float* __restrict__ shift) {
    int c = threadIdx.x;
    if (c >= 32) return;
    float mean = sums[c] / MCNT;
    float var  = sumsqs[c] / MCNT - mean * mean;
    float rstd = rsqrtf(var + 1e-5f);
    float sc = gamma[c] * rstd;
    scale[c] = sc;
    shift[c] = beta[c] - mean * sc;
}

extern "C" void kernel_launch(void* const* d_in, const int* in_sizes, int n_in,
                              void* d_out, int out_size, void* d_ws, size_t ws_size,
                              hipStream_t stream) {
    const float* x      = (const float*)d_in[0];
    const float* weight = (const float*)d_in[1];
    const float* bias   = (const float*)d_in[2];
    const float* gamma  = (const float*)d_in[3];
    const float* beta   = (const float*)d_in[4];
    float* out = (float*)d_out;
    float* wsf = (float*)d_ws;

    float* scale = wsf + FAST_SC_F;
    float* shift = wsf + FAST_SC_F + 32;
    float* part  = wsf + FAST_PART_F;
    ushort* wb   = (ushort*)(wsf + FAST_WB_F);

    if (ws_size >= FAST_BYTES_BF16Y) {
        ushort* yb = (ushort*)(wsf + FAST_YB_F);
        hipLaunchKernelGGL(conv_direct, dim3(1024), dim3(512), 0, stream,
                           x, weight, bias, yb, part);
        hipLaunchKernelGGL((stats_fast_t<1024>), dim3(1), dim3(1024), 0, stream,
                           part, gamma, beta, scale, shift);
        hipLaunchKernelGGL(bn_act_bf16, dim3(2048), dim3(256), 0, stream,
                           yb, out, scale, shift);
    } else if (ws_size >= FAST_BYTES_FP32Y) {
        ushort* xt = (ushort*)(wsf + FAST_XT_F);
        hipLaunchKernelGGL(transpose_prep, dim3(1024), dim3(256), 0, stream,
                           x, weight, xt, wb);
        hipLaunchKernelGGL(conv_mfma_f32y, dim3(1024), dim3(512), 0, stream,
                           xt, wb, bias, out, part);
        hipLaunchKernelGGL((stats_fast_t<1024>), dim3(1), dim3(1024), 0, stream,
                           part, gamma, beta, scale, shift);
        hipLaunchKernelGGL(bn_act_kernel, dim3(2048), dim3(256), 0, stream,
                           out, scale, shift);
    } else {
        hipLaunchKernelGGL(prep_weights, dim3(1), dim3(512), 0, stream, weight, wsf);
        hipLaunchKernelGGL(conv_kernel, dim3(1024), dim3(256), 0, stream,
                           x, bias, wsf + WS_W, out, wsf + WS_SUM, wsf + WS_SUMSQ);
        hipLaunchKernelGGL(stats_kernel, dim3(1), dim3(64), 0, stream,
                           gamma, beta, wsf + WS_SUM, wsf + WS_SUMSQ, wsf + WS_SCALE, wsf + WS_SHIFT);
        hipLaunchKernelGGL(bn_act_kernel, dim3(2048), dim3(256), 0, stream,
                           out, wsf + WS_SCALE, wsf + WS_SHIFT);
    }
}